// Round 5
// baseline (176.769 us; speedup 1.0000x reference)
//
#include <hip/hip_runtime.h>

// DeformableConv2D round 5: direct-to-register sampling + 8 pixels/block.
//
// prep: offset weights -> f16 transposed [80][576]; conv weights -> f16.
// main: 1568 blocks x 256 thr (4 waves), 8 pixels/block (M=8; MFMA rows 8..15
//       are computed-but-discarded garbage -- C rows are independent).
//   A : offset conv MFMA GEMM, A-frags gathered from global x (predicated),
//       waves = N-tiles (wave 3 takes tiles 3+4). Zero barriers.
//   A': coord/weight table, lane = sample; ring corners get weight 0,
//       addresses clamped in-bounds. Stored as {float4 w, int4 idx} in LDS.
//   B : lane (m,kq) gathers the 4 corners' own channel slices (float4 x2 per
//       s-half) and does the weighted sum IN REGISTERS -> af directly.
//       No s_sa LDS round trip, no barriers in the tap loop.
// Barriers per block: 2.
//
// MFMA 16x16x32 f16 layouts (verified rounds 3-4):
//   A-frag: lane holds A[m=lane&15][k=(lane>>4)*8+j]
//   B-frag: lane holds B[k=(lane>>4)*8+j][n=lane&15]   (B stored [n][k])
//   C/D  : col(n)=lane&15, row(m)=(lane>>4)*4+reg

#define NH 56
#define NW 56
#define NC 64
#define NDG 4
#define NK 9
#define NKG 36
#define NOFF 72
#define NOFFP 80
#define NF 64
#define KTOT 576
#define HWPIX 3136
#define NPIX 12544
#define PPB 8

#define WS_OFFKT 0          // f16 [80][576]   = 92160 B
#define WS_WK    92160      // f16 [9][64][64] = 73728 B

typedef _Float16 half8   __attribute__((ext_vector_type(8)));
typedef float    floatx4 __attribute__((ext_vector_type(4)));

// ---------------- prep: weight conversion ----------------
__global__ __launch_bounds__(256)
void dcn_prep(const float* __restrict__ offk,   // [3,3,64,72] (kk,oc)
              const float* __restrict__ wk,     // [3,3,64,64] (k,f,c)
              _Float16* __restrict__ offkt,     // [80][576]   (oc,kk)
              _Float16* __restrict__ wkh)       // [9][64][64]
{
    const int i = blockIdx.x * 256 + threadIdx.x;
    if (i < NOFFP * KTOT) {
        const int oc = i / KTOT;
        const int kk = i - oc * KTOT;
        const float v = (oc < NOFF) ? offk[kk * NOFF + oc] : 0.0f;
        offkt[i] = (_Float16)v;
    }
    const int j = i - NOFFP * KTOT;
    if (j >= 0 && j < NK * NF * NC) wkh[j] = (_Float16)wk[j];
}

// ---------------- fused main ----------------
__global__ __launch_bounds__(256, 8)
void dcn_main(const float* __restrict__ x,        // [4,56,56,64]
              const _Float16* __restrict__ offkt, // [80][576]
              const float* __restrict__ offb,     // [72]
              const _Float16* __restrict__ wkh,   // [9][64][64]
              float* __restrict__ out)            // [12544][64]
{
    __shared__ float s_off[PPB * NOFF];                     // 2.3 KB
    __shared__ __align__(16) float s_tab[NK * NDG * PPB * 8]; // 9.2 KB

    const int tid  = threadIdx.x;
    const int w    = tid >> 6;      // wave id: A = N-tile, B = group
    const int lane = tid & 63;
    const int m    = lane & 15;     // MFMA row/col index
    const int kq   = lane >> 4;     // MFMA k-quad
    const int pm   = m & 7;         // pixel slot (valid rows are 0..7)
    const bool mlow = (m < 8);

    const int pix0 = blockIdx.x * PPB;
    const int pixm = pix0 + pm;                 // always < NPIX
    const int bm   = pixm / HWPIX;
    const int rrm  = pixm - bm * HWPIX;
    const int ohm  = rrm / NW;
    const int owm  = rrm - ohm * NW;
    const float* xbase = x + (size_t)(bm * HWPIX + ohm * NW + owm) * NC + kq * 8;

    // ---- phase A: offset conv GEMM (M=8 in a 16-row tile), no barriers ----
    const int oc0 = w * 16 + m;
    floatx4 acc0, acc1;
    { const float bv = offb[oc0]; acc0 = (floatx4){bv, bv, bv, bv}; }
    { const float bv = (w == 3 && m < 8) ? offb[64 + m] : 0.0f;
      acc1 = (floatx4){bv, bv, bv, bv}; }

    #pragma unroll
    for (int k = 0; k < NK; ++k) {
        const int ki = k / 3, kj = k - 3 * ki;
        const int ih = ohm + ki - 1, iw = owm + kj - 1;
        const bool vld = mlow && ((unsigned)ih < NH) && ((unsigned)iw < NW);
        const float* ap = xbase + ((ki - 1) * NW + (kj - 1)) * NC;
        #pragma unroll
        for (int s = 0; s < 2; ++s) {
            float4 a0 = make_float4(0.f, 0.f, 0.f, 0.f), a1 = a0;
            if (vld) {
                a0 = *(const float4*)(ap + s * 32);
                a1 = *(const float4*)(ap + s * 32 + 4);
            }
            half8 af;
            af[0] = (_Float16)a0.x; af[1] = (_Float16)a0.y;
            af[2] = (_Float16)a0.z; af[3] = (_Float16)a0.w;
            af[4] = (_Float16)a1.x; af[5] = (_Float16)a1.y;
            af[6] = (_Float16)a1.z; af[7] = (_Float16)a1.w;
            const int kkb = k * 64 + s * 32 + kq * 8;
            const half8 bf0 = *(const half8*)&offkt[(size_t)oc0 * KTOT + kkb];
            acc0 = __builtin_amdgcn_mfma_f32_16x16x32_f16(af, bf0, acc0, 0, 0, 0);
            if (w == 3) {
                const half8 bf1 = *(const half8*)&offkt[(size_t)(64 + m) * KTOT + kkb];
                acc1 = __builtin_amdgcn_mfma_f32_16x16x32_f16(af, bf1, acc1, 0, 0, 0);
            }
        }
    }
    if (kq < 2) {           // rows 0..7 are the real pixels
        #pragma unroll
        for (int r = 0; r < 4; ++r)
            s_off[(kq * 4 + r) * NOFF + oc0] = acc0[r];
        if (w == 3 && m < 8) {
            #pragma unroll
            for (int r = 0; r < 4; ++r)
                s_off[(kq * 4 + r) * NOFF + 64 + m] = acc1[r];
        }
    }
    __syncthreads();

    // ---- phase A': coord/weight table, lane = sample (288 items) ----
    for (int i = tid; i < PPB * NKG; i += 256) {
        const int p  = i / NKG;
        const int kg = i - p * NKG;             // k*NDG + g
        const int k  = kg >> 2;
        const int g  = kg & 3;
        const int ki = k / 3, kj = k - 3 * ki;
        const int pix = pix0 + p;
        const int b   = pix / HWPIX;
        const int rr  = pix - b * HWPIX;
        const int oh  = rr / NW, ow = rr - (rr / NW) * NW;
        const float offy = s_off[p * NOFF + kg * 2 + 0];
        const float offx = s_off[p * NOFF + kg * 2 + 1];
        float yv = fminf(fmaxf((float)(oh + ki) + offy, 0.0f), 57.0f);
        float xv = fminf(fmaxf((float)(ow + kj) + offx, 0.0f), 57.0f);
        const float y0f = floorf(yv), x0f = floorf(xv);
        const int y0 = (int)y0f, x0 = (int)x0f;
        const int y1 = min(y0 + 1, 57), x1 = min(x0 + 1, 57);
        const float ly = yv - y0f,       lx = xv - x0f;
        const float hy = (float)y1 - yv, hx = (float)x1 - xv;
        const bool vy0 = (unsigned)(y0 - 1) < NH;
        const bool vy1 = (unsigned)(y1 - 1) < NH;
        const bool vx0 = (unsigned)(x0 - 1) < NW;
        const bool vx1 = (unsigned)(x1 - 1) < NW;
        const float w00 = (vy0 && vx0) ? hy * hx : 0.0f;
        const float w01 = (vy0 && vx1) ? hy * lx : 0.0f;
        const float w10 = (vy1 && vx0) ? ly * hx : 0.0f;
        const float w11 = (vy1 && vx1) ? ly * lx : 0.0f;
        const int y0c = min(max(y0 - 1, 0), NH - 1);
        const int y1c = min(max(y1 - 1, 0), NH - 1);
        const int x0c = min(max(x0 - 1, 0), NW - 1);
        const int x1c = min(max(x1 - 1, 0), NW - 1);
        const int bb = b * HWPIX;
        const int e = ((k * NDG + g) * PPB + p) * 8;
        *(float4*)&s_tab[e]     = make_float4(w00, w01, w10, w11);
        *(int4*)  &s_tab[e + 4] = make_int4((bb + y0c * NW + x0c) * NC,
                                            (bb + y0c * NW + x1c) * NC,
                                            (bb + y1c * NW + x0c) * NC,
                                            (bb + y1c * NW + x1c) * NC);
    }
    __syncthreads();

    // ---- phase B: register-direct sampling + grouped conv, no barriers ----
    floatx4 accB = (floatx4){0.f, 0.f, 0.f, 0.f};
    #pragma unroll
    for (int k = 0; k < NK; ++k) {
        const int e = ((k * NDG + w) * PPB + pm) * 8;
        const float4 cw = *(const float4*)&s_tab[e];
        const int4  ci = *(const int4*)  &s_tab[e + 4];
        #pragma unroll
        for (int s = 0; s < 2; ++s) {
            const int c = s * 32 + kq * 8;
            float4 q00a = make_float4(0.f,0.f,0.f,0.f), q00b = q00a;
            float4 q01a = q00a, q01b = q00a;
            float4 q10a = q00a, q10b = q00a;
            float4 q11a = q00a, q11b = q00a;
            if (mlow) {
                q00a = *(const float4*)(x + ci.x + c);
                q00b = *(const float4*)(x + ci.x + c + 4);
                q01a = *(const float4*)(x + ci.y + c);
                q01b = *(const float4*)(x + ci.y + c + 4);
                q10a = *(const float4*)(x + ci.z + c);
                q10b = *(const float4*)(x + ci.z + c + 4);
                q11a = *(const float4*)(x + ci.w + c);
                q11b = *(const float4*)(x + ci.w + c + 4);
            }
            float4 va, vb;
            va.x = cw.x*q00a.x; va.y = cw.x*q00a.y; va.z = cw.x*q00a.z; va.w = cw.x*q00a.w;
            vb.x = cw.x*q00b.x; vb.y = cw.x*q00b.y; vb.z = cw.x*q00b.z; vb.w = cw.x*q00b.w;
            va.x = fmaf(cw.y,q01a.x,va.x); va.y = fmaf(cw.y,q01a.y,va.y);
            va.z = fmaf(cw.y,q01a.z,va.z); va.w = fmaf(cw.y,q01a.w,va.w);
            vb.x = fmaf(cw.y,q01b.x,vb.x); vb.y = fmaf(cw.y,q01b.y,vb.y);
            vb.z = fmaf(cw.y,q01b.z,vb.z); vb.w = fmaf(cw.y,q01b.w,vb.w);
            va.x = fmaf(cw.z,q10a.x,va.x); va.y = fmaf(cw.z,q10a.y,va.y);
            va.z = fmaf(cw.z,q10a.z,va.z); va.w = fmaf(cw.z,q10a.w,va.w);
            vb.x = fmaf(cw.z,q10b.x,vb.x); vb.y = fmaf(cw.z,q10b.y,vb.y);
            vb.z = fmaf(cw.z,q10b.z,vb.z); vb.w = fmaf(cw.z,q10b.w,vb.w);
            va.x = fmaf(cw.w,q11a.x,va.x); va.y = fmaf(cw.w,q11a.y,va.y);
            va.z = fmaf(cw.w,q11a.z,va.z); va.w = fmaf(cw.w,q11a.w,va.w);
            vb.x = fmaf(cw.w,q11b.x,vb.x); vb.y = fmaf(cw.w,q11b.y,vb.y);
            vb.z = fmaf(cw.w,q11b.z,vb.z); vb.w = fmaf(cw.w,q11b.w,vb.w);
            half8 af;
            af[0] = (_Float16)va.x; af[1] = (_Float16)va.y;
            af[2] = (_Float16)va.z; af[3] = (_Float16)va.w;
            af[4] = (_Float16)vb.x; af[5] = (_Float16)vb.y;
            af[6] = (_Float16)vb.z; af[7] = (_Float16)vb.w;
            const half8 bf = *(const half8*)&wkh[(size_t)(k * NF + w * 16 + m) * NC + c];
            accB = __builtin_amdgcn_mfma_f32_16x16x32_f16(af, bf, accB, 0, 0, 0);
        }
    }

    if (kq < 2) {           // rows 0..7 are the real pixels
        #pragma unroll
        for (int r = 0; r < 4; ++r)
            out[(size_t)(pix0 + kq * 4 + r) * NF + w * 16 + m] = accB[r];
    }
}

extern "C" void kernel_launch(void* const* d_in, const int* in_sizes, int n_in,
                              void* d_out, int out_size, void* d_ws, size_t ws_size,
                              hipStream_t stream) {
    const float* xin  = (const float*)d_in[0];
    const float* offk = (const float*)d_in[1];
    const float* offb = (const float*)d_in[2];
    const float* wk   = (const float*)d_in[3];
    float* outp = (float*)d_out;

    _Float16* offkt = (_Float16*)((char*)d_ws + WS_OFFKT);
    _Float16* wkh   = (_Float16*)((char*)d_ws + WS_WK);

    dcn_prep<<<324, 256, 0, stream>>>(offk, wk, offkt, wkh);
    dcn_main<<<NPIX / PPB, 256, 0, stream>>>(xin, offkt, offb, wkh, outp);
}

// Round 6
// 136.286 us; speedup vs baseline: 1.2970x; 1.2970x over previous
//
#include <hip/hip_runtime.h>

// DeformableConv2D round 6: round-5 structure, un-spilled + f16 everywhere.
//
// prep: x -> f16 copy; offset weights -> f16 transposed [80][576];
//       conv weights -> f16.
// main: 1568 blocks x 256 thr (4 waves), 8 pixels/block (M=8; MFMA rows 8..15
//       discarded). __launch_bounds__(256,4): 128-VGPR budget, NO spilling
//       (round 5's (256,8) forced 64 and spilled ~11 MB to scratch).
//   A : offset conv MFMA GEMM; A-frag = ONE predicated half8 load from xh.
//   A': coord/weight table, lane = sample; {float4 w, int4 idx} in LDS.
//   B : per (k,s): 4 half8 corner loads + packed f16 bilinear blend
//       (v_pk_fma_f16) -> A-fragment directly, then 1 MFMA. No barriers.
//
// MFMA 16x16x32 f16 layouts (verified rounds 3-5):
//   A-frag: lane holds A[m=lane&15][k=(lane>>4)*8+j]
//   B-frag: lane holds B[k=(lane>>4)*8+j][n=lane&15]   (B stored [n][k])
//   C/D  : col(n)=lane&15, row(m)=(lane>>4)*4+reg

#define NH 56
#define NW 56
#define NC 64
#define NDG 4
#define NK 9
#define NKG 36
#define NOFF 72
#define NOFFP 80
#define NF 64
#define KTOT 576
#define HWPIX 3136
#define NPIX 12544
#define PPB 8

#define WS_OFFKT 0                      // f16 [80][576]    = 92160 B
#define WS_WK    92160                  // f16 [9][64][64]  = 73728 B
#define WS_XH    (92160 + 73728)        // f16 [12544*64]   = 1605632 B

typedef _Float16 half8   __attribute__((ext_vector_type(8)));
typedef _Float16 half4v  __attribute__((ext_vector_type(4)));
typedef float    floatx4 __attribute__((ext_vector_type(4)));

// ---------------- prep: x->f16 + weight conversion ----------------
__global__ __launch_bounds__(256)
void dcn_prep(const float* __restrict__ x,      // [12544*64]
              const float* __restrict__ offk,   // [3,3,64,72] (kk,oc)
              const float* __restrict__ wk,     // [3,3,64,64] (k,f,c)
              _Float16* __restrict__ offkt,     // [80][576]   (oc,kk)
              _Float16* __restrict__ wkh,       // [9][64][64]
              _Float16* __restrict__ xh)        // [12544*64]
{
    const int t = blockIdx.x * 256 + threadIdx.x;   // 0..200703
    // x -> f16 (4 elements/thread, exactly covers 802816)
    {
        const float4 v = *(const float4*)(x + (size_t)t * 4);
        half4v h; h[0] = (_Float16)v.x; h[1] = (_Float16)v.y;
                  h[2] = (_Float16)v.z; h[3] = (_Float16)v.w;
        *(half4v*)(xh + (size_t)t * 4) = h;
    }
    if (t < NOFFP * KTOT) {
        const int oc = t / KTOT;
        const int kk = t - oc * KTOT;
        offkt[t] = (oc < NOFF) ? (_Float16)offk[kk * NOFF + oc] : (_Float16)0.0f;
    }
    const int j = t - NOFFP * KTOT;
    if (j >= 0 && j < NK * NF * NC) wkh[j] = (_Float16)wk[j];
}

// ---------------- fused main ----------------
__global__ __launch_bounds__(256, 4)
void dcn_main(const _Float16* __restrict__ xh,    // [12544][64] f16
              const _Float16* __restrict__ offkt, // [80][576]
              const float* __restrict__ offb,     // [72]
              const _Float16* __restrict__ wkh,   // [9][64][64]
              float* __restrict__ out)            // [12544][64]
{
    __shared__ float s_off[PPB * NOFF];                       // 2.3 KB
    __shared__ __align__(16) float s_tab[NKG * PPB * 8];      // 9.2 KB

    const int tid  = threadIdx.x;
    const int w    = tid >> 6;      // wave id: A = N-tile, B = group
    const int lane = tid & 63;
    const int m    = lane & 15;
    const int kq   = lane >> 4;
    const int pm   = m & 7;         // pixel slot (rows 0..7 are real)
    const bool mlow = (m < 8);

    const int pix0 = blockIdx.x * PPB;
    const int pixm = pix0 + pm;
    const int bm   = pixm / HWPIX;
    const int rrm  = pixm - bm * HWPIX;
    const int ohm  = rrm / NW;
    const int owm  = rrm - ohm * NW;
    const _Float16* xbase = xh + (size_t)(bm * HWPIX + ohm * NW + owm) * NC + kq * 8;

    // ---- phase A: offset conv GEMM (M=8 of 16), zero barriers ----
    const int oc0 = w * 16 + m;
    floatx4 acc0, acc1;
    { const float bv = offb[oc0]; acc0 = (floatx4){bv, bv, bv, bv}; }
    { const float bv = (w == 3 && m < 8) ? offb[64 + m] : 0.0f;
      acc1 = (floatx4){bv, bv, bv, bv}; }

    #pragma unroll
    for (int k = 0; k < NK; ++k) {
        const int ki = k / 3, kj = k - 3 * ki;
        const int ih = ohm + ki - 1, iw = owm + kj - 1;
        const bool vld = mlow && ((unsigned)ih < NH) && ((unsigned)iw < NW);
        const _Float16* ap = xbase + ((ki - 1) * NW + (kj - 1)) * NC;
        #pragma unroll
        for (int s = 0; s < 2; ++s) {
            half8 af = (half8)(_Float16)0.0f;
            if (vld) af = *(const half8*)(ap + s * 32);
            const int kkb = k * 64 + s * 32 + kq * 8;
            const half8 bf0 = *(const half8*)&offkt[(size_t)oc0 * KTOT + kkb];
            acc0 = __builtin_amdgcn_mfma_f32_16x16x32_f16(af, bf0, acc0, 0, 0, 0);
            if (w == 3) {
                const half8 bf1 = *(const half8*)&offkt[(size_t)(64 + m) * KTOT + kkb];
                acc1 = __builtin_amdgcn_mfma_f32_16x16x32_f16(af, bf1, acc1, 0, 0, 0);
            }
        }
    }
    if (kq < 2) {
        #pragma unroll
        for (int r = 0; r < 4; ++r)
            s_off[(kq * 4 + r) * NOFF + oc0] = acc0[r];
        if (w == 3 && m < 8) {
            #pragma unroll
            for (int r = 0; r < 4; ++r)
                s_off[(kq * 4 + r) * NOFF + 64 + m] = acc1[r];
        }
    }
    __syncthreads();

    // ---- phase A': coord/weight table, lane = sample (288 items) ----
    for (int i = tid; i < PPB * NKG; i += 256) {
        const int p  = i / NKG;
        const int kg = i - p * NKG;             // k*NDG + g
        const int k  = kg >> 2;
        const int g  = kg & 3;
        const int ki = k / 3, kj = k - 3 * ki;
        const int pix = pix0 + p;
        const int b   = pix / HWPIX;
        const int rr  = pix - b * HWPIX;
        const int oh  = rr / NW, ow = rr - (rr / NW) * NW;
        const float offy = s_off[p * NOFF + kg * 2 + 0];
        const float offx = s_off[p * NOFF + kg * 2 + 1];
        float yv = fminf(fmaxf((float)(oh + ki) + offy, 0.0f), 57.0f);
        float xv = fminf(fmaxf((float)(ow + kj) + offx, 0.0f), 57.0f);
        const float y0f = floorf(yv), x0f = floorf(xv);
        const int y0 = (int)y0f, x0 = (int)x0f;
        const int y1 = min(y0 + 1, 57), x1 = min(x0 + 1, 57);
        const float ly = yv - y0f,       lx = xv - x0f;
        const float hy = (float)y1 - yv, hx = (float)x1 - xv;
        const bool vy0 = (unsigned)(y0 - 1) < NH;
        const bool vy1 = (unsigned)(y1 - 1) < NH;
        const bool vx0 = (unsigned)(x0 - 1) < NW;
        const bool vx1 = (unsigned)(x1 - 1) < NW;
        const float w00 = (vy0 && vx0) ? hy * hx : 0.0f;
        const float w01 = (vy0 && vx1) ? hy * lx : 0.0f;
        const float w10 = (vy1 && vx0) ? ly * hx : 0.0f;
        const float w11 = (vy1 && vx1) ? ly * lx : 0.0f;
        const int y0c = min(max(y0 - 1, 0), NH - 1);
        const int y1c = min(max(y1 - 1, 0), NH - 1);
        const int x0c = min(max(x0 - 1, 0), NW - 1);
        const int x1c = min(max(x1 - 1, 0), NW - 1);
        const int bb = b * HWPIX;
        const int e = ((k * NDG + g) * PPB + p) * 8;
        *(float4*)&s_tab[e]     = make_float4(w00, w01, w10, w11);
        *(int4*)  &s_tab[e + 4] = make_int4((bb + y0c * NW + x0c) * NC,
                                            (bb + y0c * NW + x1c) * NC,
                                            (bb + y1c * NW + x0c) * NC,
                                            (bb + y1c * NW + x1c) * NC);
    }
    __syncthreads();

    // ---- phase B: f16 register-direct sampling + grouped conv ----
    floatx4 accB = (floatx4){0.f, 0.f, 0.f, 0.f};
    #pragma unroll
    for (int k = 0; k < NK; ++k) {
        const int e = ((k * NDG + w) * PPB + pm) * 8;
        const float4 cw = *(const float4*)&s_tab[e];
        const int4  ci = *(const int4*)  &s_tab[e + 4];
        const _Float16 h00 = (_Float16)cw.x, h01 = (_Float16)cw.y;
        const _Float16 h10 = (_Float16)cw.z, h11 = (_Float16)cw.w;
        #pragma unroll
        for (int s = 0; s < 2; ++s) {
            const int c = s * 32 + kq * 8;
            half8 q00 = (half8)(_Float16)0.0f, q01 = q00, q10 = q00, q11 = q00;
            if (mlow) {
                q00 = *(const half8*)(xh + ci.x + c);
                q01 = *(const half8*)(xh + ci.y + c);
                q10 = *(const half8*)(xh + ci.z + c);
                q11 = *(const half8*)(xh + ci.w + c);
            }
            half8 af = q00 * h00;          // v_pk_mul/fma_f16 packed blend
            af += q01 * h01;
            af += q10 * h10;
            af += q11 * h11;
            const half8 bf = *(const half8*)&wkh[(size_t)(k * NF + w * 16 + m) * NC + c];
            accB = __builtin_amdgcn_mfma_f32_16x16x32_f16(af, bf, accB, 0, 0, 0);
        }
    }

    if (kq < 2) {
        #pragma unroll
        for (int r = 0; r < 4; ++r)
            out[(size_t)(pix0 + kq * 4 + r) * NF + w * 16 + m] = accB[r];
    }
}

extern "C" void kernel_launch(void* const* d_in, const int* in_sizes, int n_in,
                              void* d_out, int out_size, void* d_ws, size_t ws_size,
                              hipStream_t stream) {
    const float* xin  = (const float*)d_in[0];
    const float* offk = (const float*)d_in[1];
    const float* offb = (const float*)d_in[2];
    const float* wk   = (const float*)d_in[3];
    float* outp = (float*)d_out;

    _Float16* offkt = (_Float16*)((char*)d_ws + WS_OFFKT);
    _Float16* wkh   = (_Float16*)((char*)d_ws + WS_WK);
    _Float16* xh    = (_Float16*)((char*)d_ws + WS_XH);

    dcn_prep<<<784, 256, 0, stream>>>(xin, offk, wk, offkt, wkh, xh);
    dcn_main<<<NPIX / PPB, 256, 0, stream>>>(xh, offkt, offb, wkh, outp);
}

// Round 7
// 134.910 us; speedup vs baseline: 1.3103x; 1.0102x over previous
//
#include <hip/hip_runtime.h>

// DeformableConv2D round 7: round-6 structure + explicit 3-stage software
// pipelines (the round-6 compiler chose a 32-VGPR zero-ILP schedule; named
// rotating buffers force loads to stay in flight across consumes).
//
// prep: x -> f16; offset weights -> f16 transposed [80][576]; conv wts -> f16.
// main: 1568 blocks x 256 thr (4 waves), 8 pixels/block (M=8 of 16; rows 8..15
//       discarded). __launch_bounds__(256,4): 128-VGPR budget.
//   A : offset conv MFMA GEMM, 18 (k,s)-steps, 3-stage rotation {af,bf0,bf1}.
//   A': coord/weight table, lane = sample; split float4/int4 arrays.
//   B : 18 (k,s)-steps, 3-stage rotation {4 corners + B-frag}; coord table
//       double-buffered one k ahead. Packed f16 bilinear blend -> A-frag.
//
// MFMA 16x16x32 f16 layouts (verified rounds 3-6):
//   A-frag: lane holds A[m=lane&15][k=(lane>>4)*8+j]
//   B-frag: lane holds B[k=(lane>>4)*8+j][n=lane&15]   (B stored [n][k])
//   C/D  : col(n)=lane&15, row(m)=(lane>>4)*4+reg

#define NH 56
#define NW 56
#define NC 64
#define NDG 4
#define NK 9
#define NKG 36
#define NOFF 72
#define NOFFP 80
#define NF 64
#define KTOT 576
#define HWPIX 3136
#define NPIX 12544
#define PPB 8

#define WS_OFFKT 0                      // f16 [80][576]    = 92160 B
#define WS_WK    92160                  // f16 [9][64][64]  = 73728 B
#define WS_XH    (92160 + 73728)        // f16 [12544*64]   = 1605632 B

typedef _Float16 half8   __attribute__((ext_vector_type(8)));
typedef _Float16 half4v  __attribute__((ext_vector_type(4)));
typedef float    floatx4 __attribute__((ext_vector_type(4)));

// ---------------- prep: x->f16 + weight conversion ----------------
__global__ __launch_bounds__(256)
void dcn_prep(const float* __restrict__ x,      // [12544*64]
              const float* __restrict__ offk,   // [3,3,64,72] (kk,oc)
              const float* __restrict__ wk,     // [3,3,64,64] (k,f,c)
              _Float16* __restrict__ offkt,     // [80][576]   (oc,kk)
              _Float16* __restrict__ wkh,       // [9][64][64]
              _Float16* __restrict__ xh)        // [12544*64]
{
    const int t = blockIdx.x * 256 + threadIdx.x;   // 0..200703
    {
        const float4 v = *(const float4*)(x + (size_t)t * 4);
        half4v h; h[0] = (_Float16)v.x; h[1] = (_Float16)v.y;
                  h[2] = (_Float16)v.z; h[3] = (_Float16)v.w;
        *(half4v*)(xh + (size_t)t * 4) = h;
    }
    if (t < NOFFP * KTOT) {
        const int oc = t / KTOT;
        const int kk = t - oc * KTOT;
        offkt[t] = (oc < NOFF) ? (_Float16)offk[kk * NOFF + oc] : (_Float16)0.0f;
    }
    const int j = t - NOFFP * KTOT;
    if (j >= 0 && j < NK * NF * NC) wkh[j] = (_Float16)wk[j];
}

// ---------------- fused main ----------------
__global__ __launch_bounds__(256, 4)
void dcn_main(const _Float16* __restrict__ xh,    // [12544][64] f16
              const _Float16* __restrict__ offkt, // [80][576]
              const float* __restrict__ offb,     // [72]
              const _Float16* __restrict__ wkh,   // [9][64][64]
              float* __restrict__ out)            // [12544][64]
{
    __shared__ float s_off[PPB * NOFF];                       // 2.3 KB
    __shared__ __align__(16) float4 s_tw[NKG * PPB];          // 4.6 KB
    __shared__ __align__(16) int4   s_ti[NKG * PPB];          // 4.6 KB

    const int tid  = threadIdx.x;
    const int w    = tid >> 6;      // wave id: A = N-tile, B = group
    const int lane = tid & 63;
    const int m    = lane & 15;
    const int kq   = lane >> 4;
    const int kq8  = kq * 8;
    const int pm   = m & 7;         // pixel slot (rows 0..7 real)
    const bool mlow = (m < 8);

    const int pix0 = blockIdx.x * PPB;
    const int pixm = pix0 + pm;
    const int bm   = pixm / HWPIX;
    const int rrm  = pixm - bm * HWPIX;
    const int ohm  = rrm / NW;
    const int owm  = rrm - ohm * NW;
    const _Float16* xbase = xh + (size_t)(bm * HWPIX + ohm * NW + owm) * NC + kq8;

    // ---- phase A: offset conv GEMM, 3-stage pipeline over 18 (k,s) steps ----
    const int oc0 = w * 16 + m;
    floatx4 acc0, acc1;
    { const float bv = offb[oc0]; acc0 = (floatx4){bv, bv, bv, bv}; }
    { const float bv = (w == 3 && m < 8) ? offb[64 + m] : 0.0f;
      acc1 = (floatx4){bv, bv, bv, bv}; }

    half8 ab[3][3];

#define ALOAD(BUF, KK, SS) do {                                               \
        const int ki_ = (KK) / 3, kj_ = (KK) - 3 * ki_;                       \
        const int ih_ = ohm + ki_ - 1, iw_ = owm + kj_ - 1;                   \
        const bool v_ = mlow && ((unsigned)ih_ < NH) && ((unsigned)iw_ < NW); \
        (BUF)[0] = (half8)(_Float16)0.0f;                                     \
        if (v_) (BUF)[0] = *(const half8*)(xbase + ((ki_ - 1) * NW + (kj_ - 1)) * NC + (SS) * 32); \
        const int kkb_ = (KK) * 64 + (SS) * 32 + kq8;                         \
        (BUF)[1] = *(const half8*)&offkt[(size_t)oc0 * KTOT + kkb_];          \
        if (w == 3) (BUF)[2] = *(const half8*)&offkt[(size_t)(64 + m) * KTOT + kkb_]; \
    } while (0)

    ALOAD(ab[0], 0, 0);
    ALOAD(ab[1], 0, 1);
    #pragma unroll
    for (int t = 0; t < 18; ++t) {
        if (t + 2 < 18) {
            const int t2 = t + 2;
            ALOAD(ab[t2 % 3], t2 >> 1, t2 & 1);
        }
        acc0 = __builtin_amdgcn_mfma_f32_16x16x32_f16(ab[t % 3][0], ab[t % 3][1], acc0, 0, 0, 0);
        if (w == 3)
            acc1 = __builtin_amdgcn_mfma_f32_16x16x32_f16(ab[t % 3][0], ab[t % 3][2], acc1, 0, 0, 0);
    }
#undef ALOAD

    if (kq < 2) {
        #pragma unroll
        for (int r = 0; r < 4; ++r)
            s_off[(kq * 4 + r) * NOFF + oc0] = acc0[r];
        if (w == 3 && m < 8) {
            #pragma unroll
            for (int r = 0; r < 4; ++r)
                s_off[(kq * 4 + r) * NOFF + 64 + m] = acc1[r];
        }
    }
    __syncthreads();

    // ---- phase A': coord/weight table, lane = sample (288 items) ----
    for (int i = tid; i < PPB * NKG; i += 256) {
        const int p  = i / NKG;
        const int kg = i - p * NKG;             // k*NDG + g
        const int k  = kg >> 2;
        const int ki = k / 3, kj = k - 3 * ki;
        const int pix = pix0 + p;
        const int b   = pix / HWPIX;
        const int rr  = pix - b * HWPIX;
        const int oh  = rr / NW, ow = rr - (rr / NW) * NW;
        const float offy = s_off[p * NOFF + kg * 2 + 0];
        const float offx = s_off[p * NOFF + kg * 2 + 1];
        float yv = fminf(fmaxf((float)(oh + ki) + offy, 0.0f), 57.0f);
        float xv = fminf(fmaxf((float)(ow + kj) + offx, 0.0f), 57.0f);
        const float y0f = floorf(yv), x0f = floorf(xv);
        const int y0 = (int)y0f, x0 = (int)x0f;
        const int y1 = min(y0 + 1, 57), x1 = min(x0 + 1, 57);
        const float ly = yv - y0f,       lx = xv - x0f;
        const float hy = (float)y1 - yv, hx = (float)x1 - xv;
        const bool vy0 = (unsigned)(y0 - 1) < NH;
        const bool vy1 = (unsigned)(y1 - 1) < NH;
        const bool vx0 = (unsigned)(x0 - 1) < NW;
        const bool vx1 = (unsigned)(x1 - 1) < NW;
        const float w00 = (vy0 && vx0) ? hy * hx : 0.0f;
        const float w01 = (vy0 && vx1) ? hy * lx : 0.0f;
        const float w10 = (vy1 && vx0) ? ly * hx : 0.0f;
        const float w11 = (vy1 && vx1) ? ly * lx : 0.0f;
        const int y0c = min(max(y0 - 1, 0), NH - 1);
        const int y1c = min(max(y1 - 1, 0), NH - 1);
        const int x0c = min(max(x0 - 1, 0), NW - 1);
        const int x1c = min(max(x1 - 1, 0), NW - 1);
        const int bb = b * HWPIX;
        s_tw[kg * PPB + p] = make_float4(w00, w01, w10, w11);
        s_ti[kg * PPB + p] = make_int4((bb + y0c * NW + x0c) * NC,
                                       (bb + y0c * NW + x1c) * NC,
                                       (bb + y1c * NW + x0c) * NC,
                                       (bb + y1c * NW + x1c) * NC);
    }
    __syncthreads();

    // ---- phase B: pipelined f16 sampling + grouped conv ----
    const int fcol  = w * 16 + m;
    const int tbase = w * PPB + pm;     // table idx = k*32 + tbase
    floatx4 accB = (floatx4){0.f, 0.f, 0.f, 0.f};

    half8 buf[3][5];
    #pragma unroll
    for (int i = 0; i < 3; ++i) {
        buf[i][0] = buf[i][1] = buf[i][2] = buf[i][3] = (half8)(_Float16)0.0f;
    }

#define GATHER(BUF, CI, KK, SS) do {                                          \
        const int c_ = (SS) * 32 + kq8;                                       \
        if (mlow) {                                                           \
            (BUF)[0] = *(const half8*)(xh + (CI).x + c_);                     \
            (BUF)[1] = *(const half8*)(xh + (CI).y + c_);                     \
            (BUF)[2] = *(const half8*)(xh + (CI).z + c_);                     \
            (BUF)[3] = *(const half8*)(xh + (CI).w + c_);                     \
        }                                                                     \
        (BUF)[4] = *(const half8*)&wkh[((size_t)(KK) * NF + fcol) * NC + c_]; \
    } while (0)

    float4 cwt[2]; int4 cit[2];
    cwt[0] = s_tw[tbase];       cit[0] = s_ti[tbase];        // k=0
    cwt[1] = s_tw[tbase + 32];  cit[1] = s_ti[tbase + 32];   // k=1
    GATHER(buf[0], cit[0], 0, 0);
    GATHER(buf[1], cit[0], 0, 1);

    #pragma unroll
    for (int t = 0; t < 18; ++t) {
        const int k = t >> 1;
        if (t + 2 < 18) {
            const int t2 = t + 2, k2 = t2 >> 1;
            GATHER(buf[t2 % 3], cit[k2 & 1], k2, t2 & 1);
        }
        {
            const float4 cwv = cwt[k & 1];
            const _Float16 h0 = (_Float16)cwv.x, h1 = (_Float16)cwv.y;
            const _Float16 h2 = (_Float16)cwv.z, h3 = (_Float16)cwv.w;
            half8 af = buf[t % 3][0] * h0;
            af += buf[t % 3][1] * h1;
            af += buf[t % 3][2] * h2;
            af += buf[t % 3][3] * h3;
            accB = __builtin_amdgcn_mfma_f32_16x16x32_f16(af, buf[t % 3][4], accB, 0, 0, 0);
        }
        if ((t & 1) && (k + 2 <= 8)) {       // prefetch table for k+2
            cwt[k & 1] = s_tw[tbase + (k + 2) * 32];
            cit[k & 1] = s_ti[tbase + (k + 2) * 32];
        }
    }
#undef GATHER

    if (kq < 2) {
        #pragma unroll
        for (int r = 0; r < 4; ++r)
            out[(size_t)(pix0 + kq * 4 + r) * NF + fcol] = accB[r];
    }
}

extern "C" void kernel_launch(void* const* d_in, const int* in_sizes, int n_in,
                              void* d_out, int out_size, void* d_ws, size_t ws_size,
                              hipStream_t stream) {
    const float* xin  = (const float*)d_in[0];
    const float* offk = (const float*)d_in[1];
    const float* offb = (const float*)d_in[2];
    const float* wk   = (const float*)d_in[3];
    float* outp = (float*)d_out;

    _Float16* offkt = (_Float16*)((char*)d_ws + WS_OFFKT);
    _Float16* wkh   = (_Float16*)((char*)d_ws + WS_WK);
    _Float16* xh    = (_Float16*)((char*)d_ws + WS_XH);

    dcn_prep<<<784, 256, 0, stream>>>(xin, offk, wk, offkt, wkh, xh);
    dcn_main<<<NPIX / PPB, 256, 0, stream>>>(xh, offkt, offb, wkh, outp);
}

// Round 8
// 122.521 us; speedup vs baseline: 1.4428x; 1.1011x over previous
//
#include <hip/hip_runtime.h>

// DeformableConv2D round 8: M=16 full-tile + fully branchless hot path.
//
// R7 post-mortem: ~500 cyc/load serialized (VGPR 56 => compiler collapsed the
// pipeline; `if (mlow)` branches around load clusters blocked MLP; half of
// all MFMA rows / gathers / B-frags wasted at M=8).
// Fix: PPB=16 (784 blocks x 4 waves, all co-resident at 4 blocks/CU),
// every lane's gather serves a real pixel, loads are never predicated
// (clamped address + cndmask-zero for phase A), depth-3 rotation kept.
//
// prep: x -> f16; offset weights -> f16 transposed [80][576]; conv wts -> f16.
// main: phase A  offset conv MFMA GEMM (N-tiles over waves, wave3 also tile4)
//       phase A' coord/weight table, lane = sample, split float4/int4 LDS
//       phase B  register-direct f16 bilinear blend -> A-frag -> MFMA
//
// MFMA 16x16x32 f16 layouts (verified rounds 3-7):
//   A-frag: lane holds A[m=lane&15][k=(lane>>4)*8+j]
//   B-frag: lane holds B[k=(lane>>4)*8+j][n=lane&15]   (B stored [n][k])
//   C/D  : col(n)=lane&15, row(m)=(lane>>4)*4+reg

#define NH 56
#define NW 56
#define NC 64
#define NDG 4
#define NK 9
#define NKG 36
#define NOFF 72
#define NOFFP 80
#define NF 64
#define KTOT 576
#define HWPIX 3136
#define NPIX 12544
#define PPB 16

#define WS_OFFKT 0                      // f16 [80][576]    = 92160 B
#define WS_WK    92160                  // f16 [9][64][64]  = 73728 B
#define WS_XH    (92160 + 73728)        // f16 [12544*64]   = 1605632 B

typedef _Float16 half8   __attribute__((ext_vector_type(8)));
typedef _Float16 half4v  __attribute__((ext_vector_type(4)));
typedef float    floatx4 __attribute__((ext_vector_type(4)));

// ---------------- prep: x->f16 + weight conversion ----------------
__global__ __launch_bounds__(256)
void dcn_prep(const float* __restrict__ x,      // [12544*64]
              const float* __restrict__ offk,   // [3,3,64,72] (kk,oc)
              const float* __restrict__ wk,     // [3,3,64,64] (k,f,c)
              _Float16* __restrict__ offkt,     // [80][576]   (oc,kk)
              _Float16* __restrict__ wkh,       // [9][64][64]
              _Float16* __restrict__ xh)        // [12544*64]
{
    const int t = blockIdx.x * 256 + threadIdx.x;   // 0..200703
    {
        const float4 v = *(const float4*)(x + (size_t)t * 4);
        half4v h; h[0] = (_Float16)v.x; h[1] = (_Float16)v.y;
                  h[2] = (_Float16)v.z; h[3] = (_Float16)v.w;
        *(half4v*)(xh + (size_t)t * 4) = h;
    }
    if (t < NOFFP * KTOT) {
        const int oc = t / KTOT;
        const int kk = t - oc * KTOT;
        offkt[t] = (oc < NOFF) ? (_Float16)offk[kk * NOFF + oc] : (_Float16)0.0f;
    }
    const int j = t - NOFFP * KTOT;
    if (j >= 0 && j < NK * NF * NC) wkh[j] = (_Float16)wk[j];
}

// ---------------- fused main ----------------
__global__ __launch_bounds__(256, 4)
void dcn_main(const _Float16* __restrict__ xh,    // [12544][64] f16
              const _Float16* __restrict__ offkt, // [80][576]
              const float* __restrict__ offb,     // [72]
              const _Float16* __restrict__ wkh,   // [9][64][64]
              float* __restrict__ out)            // [12544][64]
{
    __shared__ float s_off[PPB * NOFF];                       // 4.6 KB
    __shared__ __align__(16) float4 s_tw[NKG * PPB];          // 9.2 KB
    __shared__ __align__(16) int4   s_ti[NKG * PPB];          // 9.2 KB

    const int tid  = threadIdx.x;
    const int w    = tid >> 6;      // wave id: A = N-tile, B = group
    const int lane = tid & 63;
    const int m    = lane & 15;     // pixel row AND filter col
    const int kq   = lane >> 4;
    const int kq8  = kq * 8;

    const int pix0 = blockIdx.x * PPB;
    const int pixm = pix0 + m;
    const int bm   = pixm / HWPIX;
    const int rrm  = pixm - bm * HWPIX;
    const int ohm  = rrm / NW;
    const int owm  = rrm - ohm * NW;
    const _Float16* xbase = xh + (size_t)(bm * HWPIX + ohm * NW + owm) * NC + kq8;

    // ---- phase A: offset conv GEMM, branchless loads, 3-stage rotation ----
    const int oc0 = w * 16 + m;
    floatx4 acc0, acc1;
    { const float bv = offb[oc0]; acc0 = (floatx4){bv, bv, bv, bv}; }
    { const float bv = (w == 3 && m < 8) ? offb[64 + m] : 0.0f;
      acc1 = (floatx4){bv, bv, bv, bv}; }

    half8 ab[3][3];
    const half8 hzero = (half8)(_Float16)0.0f;

#define ALOAD(BUF, KK, SS) do {                                               \
        const int ki_ = (KK) / 3, kj_ = (KK) - 3 * ki_;                       \
        const bool v_ = ((unsigned)(ohm + ki_ - 1) < NH) &&                   \
                        ((unsigned)(owm + kj_ - 1) < NW);                     \
        const int off_ = v_ ? ((ki_ - 1) * NW + (kj_ - 1)) * NC : 0;          \
        const half8 ld_ = *(const half8*)(xbase + off_ + (SS) * 32);          \
        (BUF)[0] = v_ ? ld_ : hzero;                                          \
        const int kkb_ = (KK) * 64 + (SS) * 32 + kq8;                         \
        (BUF)[1] = *(const half8*)&offkt[(size_t)oc0 * KTOT + kkb_];          \
        (BUF)[2] = *(const half8*)&offkt[(size_t)(64 + m) * KTOT + kkb_];     \
    } while (0)

    ALOAD(ab[0], 0, 0);
    ALOAD(ab[1], 0, 1);
    #pragma unroll
    for (int t = 0; t < 18; ++t) {
        if (t + 2 < 18) {
            const int t2 = t + 2;
            ALOAD(ab[t2 % 3], t2 >> 1, t2 & 1);
        }
        acc0 = __builtin_amdgcn_mfma_f32_16x16x32_f16(ab[t % 3][0], ab[t % 3][1], acc0, 0, 0, 0);
        if (w == 3)
            acc1 = __builtin_amdgcn_mfma_f32_16x16x32_f16(ab[t % 3][0], ab[t % 3][2], acc1, 0, 0, 0);
    }
#undef ALOAD

    #pragma unroll
    for (int r = 0; r < 4; ++r)
        s_off[(kq * 4 + r) * NOFF + oc0] = acc0[r];
    if (w == 3 && m < 8) {
        #pragma unroll
        for (int r = 0; r < 4; ++r)
            s_off[(kq * 4 + r) * NOFF + 64 + m] = acc1[r];
    }
    __syncthreads();

    // ---- phase A': coord/weight table, lane = sample (576 items) ----
    for (int i = tid; i < PPB * NKG; i += 256) {
        const int p  = i / NKG;
        const int kg = i - p * NKG;             // k*NDG + g
        const int k  = kg >> 2;
        const int ki = k / 3, kj = k - 3 * ki;
        const int pix = pix0 + p;
        const int b   = pix / HWPIX;
        const int rr  = pix - b * HWPIX;
        const int oh  = rr / NW, ow = rr - (rr / NW) * NW;
        const float offy = s_off[p * NOFF + kg * 2 + 0];
        const float offx = s_off[p * NOFF + kg * 2 + 1];
        float yv = fminf(fmaxf((float)(oh + ki) + offy, 0.0f), 57.0f);
        float xv = fminf(fmaxf((float)(ow + kj) + offx, 0.0f), 57.0f);
        const float y0f = floorf(yv), x0f = floorf(xv);
        const int y0 = (int)y0f, x0 = (int)x0f;
        const int y1 = min(y0 + 1, 57), x1 = min(x0 + 1, 57);
        const float ly = yv - y0f,       lx = xv - x0f;
        const float hy = (float)y1 - yv, hx = (float)x1 - xv;
        const bool vy0 = (unsigned)(y0 - 1) < NH;
        const bool vy1 = (unsigned)(y1 - 1) < NH;
        const bool vx0 = (unsigned)(x0 - 1) < NW;
        const bool vx1 = (unsigned)(x1 - 1) < NW;
        const float w00 = (vy0 && vx0) ? hy * hx : 0.0f;
        const float w01 = (vy0 && vx1) ? hy * lx : 0.0f;
        const float w10 = (vy1 && vx0) ? ly * hx : 0.0f;
        const float w11 = (vy1 && vx1) ? ly * lx : 0.0f;
        const int y0c = min(max(y0 - 1, 0), NH - 1);
        const int y1c = min(max(y1 - 1, 0), NH - 1);
        const int x0c = min(max(x0 - 1, 0), NW - 1);
        const int x1c = min(max(x1 - 1, 0), NW - 1);
        const int bb = b * HWPIX;
        s_tw[kg * PPB + p] = make_float4(w00, w01, w10, w11);
        s_ti[kg * PPB + p] = make_int4((bb + y0c * NW + x0c) * NC,
                                       (bb + y0c * NW + x1c) * NC,
                                       (bb + y1c * NW + x0c) * NC,
                                       (bb + y1c * NW + x1c) * NC);
    }
    __syncthreads();

    // ---- phase B: branchless register-direct sampling + grouped conv ----
    const int fcol  = w * 16 + m;       // filter col; group(fcol) == w
    const int tbase = w * PPB + m;      // table idx = k*(NDG*PPB) + tbase
    floatx4 accB = (floatx4){0.f, 0.f, 0.f, 0.f};

    half8 buf[3][5];

#define GATHER(BUF, CI, KK, SS) do {                                          \
        const int c_ = (SS) * 32 + kq8;                                       \
        (BUF)[0] = *(const half8*)(xh + (CI).x + c_);                         \
        (BUF)[1] = *(const half8*)(xh + (CI).y + c_);                         \
        (BUF)[2] = *(const half8*)(xh + (CI).z + c_);                         \
        (BUF)[3] = *(const half8*)(xh + (CI).w + c_);                         \
        (BUF)[4] = *(const half8*)&wkh[((size_t)(KK) * NF + fcol) * NC + c_]; \
    } while (0)

    float4 cwt[2]; int4 cit[2];
    cwt[0] = s_tw[tbase];                  cit[0] = s_ti[tbase];                  // k=0
    cwt[1] = s_tw[tbase + NDG * PPB];      cit[1] = s_ti[tbase + NDG * PPB];      // k=1
    GATHER(buf[0], cit[0], 0, 0);
    GATHER(buf[1], cit[0], 0, 1);

    #pragma unroll
    for (int t = 0; t < 18; ++t) {
        const int k = t >> 1;
        if (t + 2 < 18) {
            const int t2 = t + 2, k2 = t2 >> 1;
            GATHER(buf[t2 % 3], cit[k2 & 1], k2, t2 & 1);
        }
        {
            const float4 cwv = cwt[k & 1];
            const _Float16 h0 = (_Float16)cwv.x, h1 = (_Float16)cwv.y;
            const _Float16 h2 = (_Float16)cwv.z, h3 = (_Float16)cwv.w;
            half8 af = buf[t % 3][0] * h0;
            af += buf[t % 3][1] * h1;
            af += buf[t % 3][2] * h2;
            af += buf[t % 3][3] * h3;
            accB = __builtin_amdgcn_mfma_f32_16x16x32_f16(af, buf[t % 3][4], accB, 0, 0, 0);
        }
        if ((t & 1) && (k + 2 <= 8)) {       // prefetch table for k+2
            cwt[k & 1] = s_tw[tbase + (k + 2) * NDG * PPB];
            cit[k & 1] = s_ti[tbase + (k + 2) * NDG * PPB];
        }
    }
#undef GATHER

    #pragma unroll
    for (int r = 0; r < 4; ++r)
        out[(size_t)(pix0 + kq * 4 + r) * NF + fcol] = accB[r];
}

extern "C" void kernel_launch(void* const* d_in, const int* in_sizes, int n_in,
                              void* d_out, int out_size, void* d_ws, size_t ws_size,
                              hipStream_t stream) {
    const float* xin  = (const float*)d_in[0];
    const float* offk = (const float*)d_in[1];
    const float* offb = (const float*)d_in[2];
    const float* wk   = (const float*)d_in[3];
    float* outp = (float*)d_out;

    _Float16* offkt = (_Float16*)((char*)d_ws + WS_OFFKT);
    _Float16* wkh   = (_Float16*)((char*)d_ws + WS_WK);
    _Float16* xh    = (_Float16*)((char*)d_ws + WS_XH);

    dcn_prep<<<784, 256, 0, stream>>>(xin, offk, wk, offkt, wkh, xh);
    dcn_main<<<NPIX / PPB, 256, 0, stream>>>(xh, offkt, offb, wkh, outp);
}

// Round 9
// 121.183 us; speedup vs baseline: 1.4587x; 1.0110x over previous
//
#include <hip/hip_runtime.h>

// DeformableConv2D round 9: TLP restructure. R6-R8 proved the compiler
// serializes gathers regardless of source-level pipelining (VGPR stays
// 32-56, vmcnt drained at each use). So: shorten each wave's serial chain
// and raise resident waves instead.
//
// main: 784 blocks x 1024 thr (16 waves), 16 pixels/block.
//   A : offset GEMM's 5 N-tiles x 18 (k,s)-steps split (tile, third) over
//       15 waves -> 6-step chains; partial C reduced via LDS (+bias there).
//   A': coord/weight table, thread = sample (576 of 1024 threads).
//   B : (group, quarter) over 16 waves -> 4..5-step chains; partial C
//       reduced via LDS.
//   Occupancy: 2 blocks/CU x 16 waves = 32 waves/CU; LDS 39.4 KB;
//   __launch_bounds__(1024,2) => 64-VGPR cap, bodies are lean (no spill).
//
// MFMA 16x16x32 f16 layouts (verified rounds 3-8):
//   A-frag: lane holds A[m=lane&15][k=(lane>>4)*8+j]
//   B-frag: lane holds B[k=(lane>>4)*8+j][n=lane&15]   (B stored [n][k])
//   C/D  : col(n)=lane&15, row(m)=(lane>>4)*4+reg

#define NH 56
#define NW 56
#define NC 64
#define NDG 4
#define NK 9
#define NKG 36
#define NOFF 72
#define NOFFP 80
#define NF 64
#define KTOT 576
#define HWPIX 3136
#define NPIX 12544
#define PPB 16

#define WS_OFFKT 0                      // f16 [80][576]    = 92160 B
#define WS_WK    92160                  // f16 [9][64][64]  = 73728 B
#define WS_XH    (92160 + 73728)        // f16 [12544*64]   = 1605632 B

typedef _Float16 half8   __attribute__((ext_vector_type(8)));
typedef _Float16 half4v  __attribute__((ext_vector_type(4)));
typedef float    floatx4 __attribute__((ext_vector_type(4)));

// ---------------- prep: x->f16 + weight conversion ----------------
__global__ __launch_bounds__(256)
void dcn_prep(const float* __restrict__ x,      // [12544*64]
              const float* __restrict__ offk,   // [3,3,64,72] (kk,oc)
              const float* __restrict__ wk,     // [3,3,64,64] (k,f,c)
              _Float16* __restrict__ offkt,     // [80][576]   (oc,kk)
              _Float16* __restrict__ wkh,       // [9][64][64]
              _Float16* __restrict__ xh)        // [12544*64]
{
    const int t = blockIdx.x * 256 + threadIdx.x;   // 0..200703
    {
        const float4 v = *(const float4*)(x + (size_t)t * 4);
        half4v h; h[0] = (_Float16)v.x; h[1] = (_Float16)v.y;
                  h[2] = (_Float16)v.z; h[3] = (_Float16)v.w;
        *(half4v*)(xh + (size_t)t * 4) = h;
    }
    if (t < NOFFP * KTOT) {
        const int oc = t / KTOT;
        const int kk = t - oc * KTOT;
        offkt[t] = (oc < NOFF) ? (_Float16)offk[kk * NOFF + oc] : (_Float16)0.0f;
    }
    const int j = t - NOFFP * KTOT;
    if (j >= 0 && j < NK * NF * NC) wkh[j] = (_Float16)wk[j];
}

// ---------------- fused main ----------------
__global__ __launch_bounds__(1024, 2)
void dcn_main(const _Float16* __restrict__ xh,    // [12544][64] f16
              const _Float16* __restrict__ offkt, // [80][576]
              const float* __restrict__ offb,     // [72]
              const _Float16* __restrict__ wkh,   // [9][64][64]
              float* __restrict__ out)            // [12544][64]
{
    __shared__ float s_off[PPB * NOFF];                  // 4.6 KB
    __shared__ __align__(16) float4 s_tw[NKG * PPB];     // 9.2 KB
    __shared__ __align__(16) int4   s_ti[NKG * PPB];     // 9.2 KB
    __shared__ __align__(16) floatx4 s_red[16 * 64];     // 16 KB (A & B reduce)

    const int tid  = threadIdx.x;
    const int w    = tid >> 6;      // wave id 0..15
    const int lane = tid & 63;
    const int m    = lane & 15;
    const int kq   = lane >> 4;
    const int kq8  = kq * 8;

    const int pix0 = blockIdx.x * PPB;
    const int pixm = pix0 + m;
    const int bm   = pixm / HWPIX;
    const int rrm  = pixm - bm * HWPIX;
    const int ohm  = rrm / NW;
    const int owm  = rrm - ohm * NW;
    const _Float16* xbase = xh + (size_t)(bm * HWPIX + ohm * NW + owm) * NC + kq8;
    const half8 hzero = (half8)(_Float16)0.0f;

    // ---- phase A: offset GEMM, wave = (tile, third) ----
    if (w < 15) {
        const int tA = w / 3;           // N-tile 0..4
        const int qA = w - tA * 3;      // third 0..2
        const int oc0 = tA * 16 + m;
        floatx4 acc = (floatx4){0.f, 0.f, 0.f, 0.f};
        for (int t = qA * 6; t < qA * 6 + 6; ++t) {
            const int k = t >> 1, s = t & 1;
            const int ki = k / 3, kj = k - 3 * ki;
            const bool v = ((unsigned)(ohm + ki - 1) < NH) &&
                           ((unsigned)(owm + kj - 1) < NW);
            const int off = v ? ((ki - 1) * NW + (kj - 1)) * NC : 0;
            half8 af = *(const half8*)(xbase + off + s * 32);
            af = v ? af : hzero;
            const half8 bf = *(const half8*)&offkt[(size_t)oc0 * KTOT +
                                                   k * 64 + s * 32 + kq8];
            acc = __builtin_amdgcn_mfma_f32_16x16x32_f16(af, bf, acc, 0, 0, 0);
        }
        s_red[w * 64 + lane] = acc;
    }
    __syncthreads();

    // ---- reduce A -> s_off (+bias) ----
    if (tid < 320) {
        const int t = tid >> 6;         // tile
        const int l = tid & 63;
        const int oc = t * 16 + (l & 15);
        if (oc < NOFF) {
            const floatx4 v = s_red[(t * 3 + 0) * 64 + l] +
                              s_red[(t * 3 + 1) * 64 + l] +
                              s_red[(t * 3 + 2) * 64 + l];
            const float bv = offb[oc];
            const int p0 = (l >> 4) * 4;
            #pragma unroll
            for (int r = 0; r < 4; ++r)
                s_off[(p0 + r) * NOFF + oc] = v[r] + bv;
        }
    }
    __syncthreads();

    // ---- phase A': coord/weight table, thread = sample ----
    if (tid < PPB * NKG) {
        const int i  = tid;
        const int p  = i / NKG;
        const int kg = i - p * NKG;             // k*NDG + g
        const int k  = kg >> 2;
        const int ki = k / 3, kj = k - 3 * ki;
        const int pix = pix0 + p;
        const int b   = pix / HWPIX;
        const int rr  = pix - b * HWPIX;
        const int oh  = rr / NW, ow = rr - (rr / NW) * NW;
        const float offy = s_off[p * NOFF + kg * 2 + 0];
        const float offx = s_off[p * NOFF + kg * 2 + 1];
        float yv = fminf(fmaxf((float)(oh + ki) + offy, 0.0f), 57.0f);
        float xv = fminf(fmaxf((float)(ow + kj) + offx, 0.0f), 57.0f);
        const float y0f = floorf(yv), x0f = floorf(xv);
        const int y0 = (int)y0f, x0 = (int)x0f;
        const int y1 = min(y0 + 1, 57), x1 = min(x0 + 1, 57);
        const float ly = yv - y0f,       lx = xv - x0f;
        const float hy = (float)y1 - yv, hx = (float)x1 - xv;
        const bool vy0 = (unsigned)(y0 - 1) < NH;
        const bool vy1 = (unsigned)(y1 - 1) < NH;
        const bool vx0 = (unsigned)(x0 - 1) < NW;
        const bool vx1 = (unsigned)(x1 - 1) < NW;
        const float w00 = (vy0 && vx0) ? hy * hx : 0.0f;
        const float w01 = (vy0 && vx1) ? hy * lx : 0.0f;
        const float w10 = (vy1 && vx0) ? ly * hx : 0.0f;
        const float w11 = (vy1 && vx1) ? ly * lx : 0.0f;
        const int y0c = min(max(y0 - 1, 0), NH - 1);
        const int y1c = min(max(y1 - 1, 0), NH - 1);
        const int x0c = min(max(x0 - 1, 0), NW - 1);
        const int x1c = min(max(x1 - 1, 0), NW - 1);
        const int bb = b * HWPIX;
        s_tw[kg * PPB + p] = make_float4(w00, w01, w10, w11);
        s_ti[kg * PPB + p] = make_int4((bb + y0c * NW + x0c) * NC,
                                       (bb + y0c * NW + x1c) * NC,
                                       (bb + y1c * NW + x0c) * NC,
                                       (bb + y1c * NW + x1c) * NC);
    }
    __syncthreads();

    // ---- phase B: wave = (group, quarter) ----
    {
        const int g  = w & 3;
        const int q  = w >> 2;
        const int fcol = g * 16 + m;
        const int bst  = (q < 2) ? q * 5 : 10 + (q - 2) * 4;
        const int bcnt = (q < 2) ? 5 : 4;
        floatx4 acc = (floatx4){0.f, 0.f, 0.f, 0.f};
        for (int t = bst; t < bst + bcnt; ++t) {
            const int k = t >> 1, s = t & 1;
            const int e = k * (NDG * PPB) + g * PPB + m;
            const float4 cw = s_tw[e];
            const int4  ci = s_ti[e];
            const int c = s * 32 + kq8;
            const half8 q00 = *(const half8*)(xh + ci.x + c);
            const half8 q01 = *(const half8*)(xh + ci.y + c);
            const half8 q10 = *(const half8*)(xh + ci.z + c);
            const half8 q11 = *(const half8*)(xh + ci.w + c);
            const half8 bf  = *(const half8*)&wkh[((size_t)k * NF + fcol) * NC + c];
            half8 af = q00 * (_Float16)cw.x;
            af += q01 * (_Float16)cw.y;
            af += q10 * (_Float16)cw.z;
            af += q11 * (_Float16)cw.w;
            acc = __builtin_amdgcn_mfma_f32_16x16x32_f16(af, bf, acc, 0, 0, 0);
        }
        s_red[w * 64 + lane] = acc;     // slot w = q*4+g
    }
    __syncthreads();

    // ---- reduce B -> out ----
    if (tid < 256) {
        const int g = tid >> 6;
        const int l = tid & 63;
        const floatx4 v = s_red[(0 * 4 + g) * 64 + l] +
                          s_red[(1 * 4 + g) * 64 + l] +
                          s_red[(2 * 4 + g) * 64 + l] +
                          s_red[(3 * 4 + g) * 64 + l];
        const int col = g * 16 + (l & 15);
        const int p0  = (l >> 4) * 4;
        #pragma unroll
        for (int r = 0; r < 4; ++r)
            out[(size_t)(pix0 + p0 + r) * NF + col] = v[r];
    }
}

extern "C" void kernel_launch(void* const* d_in, const int* in_sizes, int n_in,
                              void* d_out, int out_size, void* d_ws, size_t ws_size,
                              hipStream_t stream) {
    const float* xin  = (const float*)d_in[0];
    const float* offk = (const float*)d_in[1];
    const float* offb = (const float*)d_in[2];
    const float* wk   = (const float*)d_in[3];
    float* outp = (float*)d_out;

    _Float16* offkt = (_Float16*)((char*)d_ws + WS_OFFKT);
    _Float16* wkh   = (_Float16*)((char*)d_ws + WS_WK);
    _Float16* xh    = (_Float16*)((char*)d_ws + WS_XH);

    dcn_prep<<<784, 256, 0, stream>>>(xin, offk, wk, offkt, wkh, xh);
    dcn_main<<<NPIX / PPB, 1024, 0, stream>>>(xh, offkt, offb, wkh, outp);
}